// Round 1
// baseline (703.366 us; speedup 1.0000x reference)
//
#include <hip/hip_runtime.h>
#include <math.h>

#define BB   64
#define SS   4096
#define ENC  512
#define DEC  512
#define NSPLIT 32
#define CHUNK (SS / NSPLIT)   // 128 rows per chunk; each of 4 waves owns 32 consecutive rows

// ---------------------------------------------------------------------------
// Kernel 1: sub[b,e] = sum_d dec[b,d] * W[e,d]     (F.linear: dec @ W^T)
// grid (4, B), block 256 (4 waves). Each wave computes 32 outputs e.
// ---------------------------------------------------------------------------
__global__ __launch_bounds__(256) void k_sub(const float* __restrict__ dec,
                                             const float* __restrict__ W,
                                             float* __restrict__ sub) {
    const int b    = blockIdx.y;
    const int lane = threadIdx.x & 63;
    const int wave = threadIdx.x >> 6;

    const float4* dv = (const float4*)(dec + (size_t)b * DEC);
    float4 q0 = dv[lane];
    float4 q1 = dv[lane + 64];

    const int e0 = blockIdx.x * 128 + wave * 32;
    for (int i = 0; i < 32; ++i) {
        const int e = e0 + i;
        const float4* wv = (const float4*)(W + (size_t)e * DEC);
        float4 w0 = wv[lane];
        float4 w1 = wv[lane + 64];
        float p = q0.x * w0.x + q0.y * w0.y + q0.z * w0.z + q0.w * w0.w
                + q1.x * w1.x + q1.y * w1.y + q1.z * w1.z + q1.w * w1.w;
        #pragma unroll
        for (int off = 32; off >= 1; off >>= 1) p += __shfl_xor(p, off, 64);
        if (lane == 0) sub[(size_t)b * ENC + e] = p;
    }
}

// ---------------------------------------------------------------------------
// Kernel 2: fused scores + online softmax + weighted accumulation.
// grid (NSPLIT, B), block 256 (4 waves). Each wave streams 32 CONSECUTIVE rows
// in 8 iterations of 4 rows:
//   - explicit register double-buffer: loads for iter j+1 issue before the
//     reduce/softmax of iter j (vmcnt decoupled from the lgkm shuffle chain)
//   - packed pair-reduce: 2 rows share one butterfly -> 4 shuffles/row (was 6)
//   - ONE merged online-softmax chain per wave: per 4 rows, 1 rescale exp +
//     4 weight exps (1.25 exp/row, was 2/row), single accumulator set
//   - raw scores stored as one float4 per iteration (was 2 scalar stores/2 rows)
// ---------------------------------------------------------------------------
__global__ __launch_bounds__(256) void k_attn(const float* __restrict__ enc,
                                              const float* __restrict__ sub,
                                              float* __restrict__ attn_raw,
                                              float* __restrict__ chunk_m,
                                              float* __restrict__ chunk_l,
                                              float* __restrict__ chunk_acc) {
    const int b    = blockIdx.y;
    const int c    = blockIdx.x;
    const int lane = threadIdx.x & 63;
    const int wave = threadIdx.x >> 6;

    const float4* qv = (const float4*)(sub + (size_t)b * ENC);
    float4 q0 = qv[lane];          // dims [4*lane .. 4*lane+3]
    float4 q1 = qv[lane + 64];     // dims [256+4*lane .. 256+4*lane+3]

    const int rowBase = c * CHUNK + wave * 32;
    const float4* base = (const float4*)(enc + ((size_t)b * SS + rowBase) * ENC);
    // row stride = ENC/4 = 128 float4

    float m = -INFINITY, l = 0.f;
    float4 a0 = {0, 0, 0, 0}, a1 = {0, 0, 0, 0};

    float4 buf[2][4][2];
    #pragma unroll
    for (int r = 0; r < 4; ++r) {
        const float4* ev = base + (size_t)r * (ENC / 4);
        buf[0][r][0] = ev[lane];
        buf[0][r][1] = ev[lane + 64];
    }

    #pragma unroll
    for (int j = 0; j < 8; ++j) {
        const int cb = j & 1;
        const int nb = cb ^ 1;
        if (j < 7) {   // prefetch next 4 rows into the other buffer
            #pragma unroll
            for (int r = 0; r < 4; ++r) {
                const float4* ev = base + (size_t)(4 * (j + 1) + r) * (ENC / 4);
                buf[nb][r][0] = ev[lane];
                buf[nb][r][1] = ev[lane + 64];
            }
        }

        // per-lane partial dots for the 4 current rows
        float p0, p1, p2, p3;
        {
            const float4 e0 = buf[cb][0][0], e1 = buf[cb][0][1];
            p0 = q0.x * e0.x + q0.y * e0.y + q0.z * e0.z + q0.w * e0.w
               + q1.x * e1.x + q1.y * e1.y + q1.z * e1.z + q1.w * e1.w;
        }
        {
            const float4 e0 = buf[cb][1][0], e1 = buf[cb][1][1];
            p1 = q0.x * e0.x + q0.y * e0.y + q0.z * e0.z + q0.w * e0.w
               + q1.x * e1.x + q1.y * e1.y + q1.z * e1.z + q1.w * e1.w;
        }
        {
            const float4 e0 = buf[cb][2][0], e1 = buf[cb][2][1];
            p2 = q0.x * e0.x + q0.y * e0.y + q0.z * e0.z + q0.w * e0.w
               + q1.x * e1.x + q1.y * e1.y + q1.z * e1.z + q1.w * e1.w;
        }
        {
            const float4 e0 = buf[cb][3][0], e1 = buf[cb][3][1];
            p3 = q0.x * e0.x + q0.y * e0.y + q0.z * e0.z + q0.w * e0.w
               + q1.x * e1.x + q1.y * e1.y + q1.z * e1.z + q1.w * e1.w;
        }

        // packed pair-reduce: rows (0,1) share one butterfly, rows (2,3) another.
        // Result: s0..s3 = full row sums, broadcast to all 64 lanes.
        float s0, s1, s2, s3;
        {
            const float tA = __shfl_xor(p0, 32, 64);
            const float tB = __shfl_xor(p1, 32, 64);
            float u = (lane < 32) ? (p0 + tA) : (p1 + tB);
            #pragma unroll
            for (int off = 16; off >= 1; off >>= 1) u += __shfl_xor(u, off, 64);
            const float v = __shfl_xor(u, 32, 64);
            s0 = (lane < 32) ? u : v;
            s1 = (lane < 32) ? v : u;
        }
        {
            const float tA = __shfl_xor(p2, 32, 64);
            const float tB = __shfl_xor(p3, 32, 64);
            float u = (lane < 32) ? (p2 + tA) : (p3 + tB);
            #pragma unroll
            for (int off = 16; off >= 1; off >>= 1) u += __shfl_xor(u, off, 64);
            const float v = __shfl_xor(u, 32, 64);
            s2 = (lane < 32) ? u : v;
            s3 = (lane < 32) ? v : u;
        }

        if (lane == 0) {
            *(float4*)&attn_raw[(size_t)b * SS + rowBase + 4 * j] =
                make_float4(s0, s1, s2, s3);
        }

        // merged online-softmax update for the 4 rows
        const float mt = fmaxf(fmaxf(s0, s1), fmaxf(s2, s3));
        const float mn = fmaxf(m, mt);
        const float sc = __expf(m - mn);          // exp(-inf)=0 on first iter
        const float w0 = __expf(s0 - mn);
        const float w1 = __expf(s1 - mn);
        const float w2 = __expf(s2 - mn);
        const float w3 = __expf(s3 - mn);
        l = l * sc + ((w0 + w1) + (w2 + w3));

        const float4 e00 = buf[cb][0][0], e01 = buf[cb][0][1];
        const float4 e10 = buf[cb][1][0], e11 = buf[cb][1][1];
        const float4 e20 = buf[cb][2][0], e21 = buf[cb][2][1];
        const float4 e30 = buf[cb][3][0], e31 = buf[cb][3][1];

        a0.x = a0.x * sc + w0 * e00.x + w1 * e10.x + w2 * e20.x + w3 * e30.x;
        a0.y = a0.y * sc + w0 * e00.y + w1 * e10.y + w2 * e20.y + w3 * e30.y;
        a0.z = a0.z * sc + w0 * e00.z + w1 * e10.z + w2 * e20.z + w3 * e30.z;
        a0.w = a0.w * sc + w0 * e00.w + w1 * e10.w + w2 * e20.w + w3 * e30.w;
        a1.x = a1.x * sc + w0 * e01.x + w1 * e11.x + w2 * e21.x + w3 * e31.x;
        a1.y = a1.y * sc + w0 * e01.y + w1 * e11.y + w2 * e21.y + w3 * e31.y;
        a1.z = a1.z * sc + w0 * e01.z + w1 * e11.z + w2 * e21.z + w3 * e31.z;
        a1.w = a1.w * sc + w0 * e01.w + w1 * e11.w + w2 * e21.w + w3 * e31.w;

        m = mn;
    }

    // ---- combine the 4 waves of this block ----
    __shared__ float sm[4];
    __shared__ float sl[4];
    __shared__ float sacc[4][ENC];

    if (lane == 0) sm[wave] = m;
    __syncthreads();
    const float M = fmaxf(fmaxf(sm[0], sm[1]), fmaxf(sm[2], sm[3]));
    const float f = __expf(m - M);            // wave-uniform
    if (lane == 0) sl[wave] = l * f;
    float* sa = &sacc[wave][0];
    sa[4 * lane + 0]       = a0.x * f;  sa[4 * lane + 1]       = a0.y * f;
    sa[4 * lane + 2]       = a0.z * f;  sa[4 * lane + 3]       = a0.w * f;
    sa[256 + 4 * lane + 0] = a1.x * f;  sa[256 + 4 * lane + 1] = a1.y * f;
    sa[256 + 4 * lane + 2] = a1.z * f;  sa[256 + 4 * lane + 3] = a1.w * f;
    __syncthreads();

    const size_t idx = (size_t)b * NSPLIT + c;
    if (threadIdx.x == 0) {
        chunk_m[idx] = M;
        chunk_l[idx] = sl[0] + sl[1] + sl[2] + sl[3];
    }
    for (int e = threadIdx.x; e < ENC; e += 256) {
        chunk_acc[idx * ENC + e] = sacc[0][e] + sacc[1][e] + sacc[2][e] + sacc[3][e];
    }
}

// ---------------------------------------------------------------------------
// Kernel 3: combine chunks -> sumResult; normalize attn in place.
// grid (B, NSPLIT), block 256. y==0 also produces sumResult.
// ---------------------------------------------------------------------------
__global__ __launch_bounds__(256) void k_final(const float* __restrict__ chunk_m,
                                               const float* __restrict__ chunk_l,
                                               const float* __restrict__ chunk_acc,
                                               float* __restrict__ attn,
                                               float* __restrict__ sumResult) {
    const int b = blockIdx.x;
    const int y = blockIdx.y;

    float M = -INFINITY;
    #pragma unroll
    for (int c = 0; c < NSPLIT; ++c) M = fmaxf(M, chunk_m[(size_t)b * NSPLIT + c]);
    float L = 0.f;
    #pragma unroll
    for (int c = 0; c < NSPLIT; ++c)
        L += chunk_l[(size_t)b * NSPLIT + c] * __expf(chunk_m[(size_t)b * NSPLIT + c] - M);
    const float invL = 1.f / L;

    if (y == 0) {
        float f[NSPLIT];
        #pragma unroll
        for (int c = 0; c < NSPLIT; ++c)
            f[c] = __expf(chunk_m[(size_t)b * NSPLIT + c] - M);
        for (int e = threadIdx.x; e < ENC; e += 256) {
            float s = 0.f;
            #pragma unroll
            for (int c = 0; c < NSPLIT; ++c)
                s += chunk_acc[((size_t)b * NSPLIT + c) * ENC + e] * f[c];
            sumResult[(size_t)b * ENC + e] = s * invL;
        }
    }

    const int s0 = y * (SS / NSPLIT);   // 128-wide slice
    for (int s = s0 + threadIdx.x; s < s0 + SS / NSPLIT; s += 256) {
        const size_t i = (size_t)b * SS + s;
        attn[i] = __expf(attn[i] - M) * invL;
    }
}

// ---------------------------------------------------------------------------
extern "C" void kernel_launch(void* const* d_in, const int* in_sizes, int n_in,
                              void* d_out, int out_size, void* d_ws, size_t ws_size,
                              hipStream_t stream) {
    const float* dec = (const float*)d_in[0];   // [B,1,DEC]
    const float* enc = (const float*)d_in[1];   // [B,S,ENC]
    const float* W   = (const float*)d_in[2];   // [ENC,DEC]

    float* out       = (float*)d_out;
    float* attn      = out;                               // B*S
    float* sumResult = out + (size_t)BB * SS;             // B*ENC

    float* ws        = (float*)d_ws;
    float* sub       = ws;                                // B*ENC
    float* chunk_m   = sub + (size_t)BB * ENC;            // B*NSPLIT
    float* chunk_l   = chunk_m + (size_t)BB * NSPLIT;     // B*NSPLIT
    float* chunk_acc = chunk_l + (size_t)BB * NSPLIT;     // B*NSPLIT*ENC

    k_sub  <<<dim3(4, BB),       256, 0, stream>>>(dec, W, sub);
    k_attn <<<dim3(NSPLIT, BB),  256, 0, stream>>>(enc, sub, attn, chunk_m, chunk_l, chunk_acc);
    k_final<<<dim3(BB, NSPLIT),  256, 0, stream>>>(chunk_m, chunk_l, chunk_acc, attn, sumResult);
}